// Round 1
// baseline (311.497 us; speedup 1.0000x reference)
//
#include <hip/hip_runtime.h>
#include <math.h>

#define HALF 64
#define LN_EPS 1e-5f

// gelu_tanh(x) = x * sigmoid(1.5957691*x + 0.0713549*x^3)
#define GC0 -2.3022082f
#define GC1 -0.1029438f

__device__ __forceinline__ float gelu_fast(float x) {
    const float x2 = x * x;
    const float z  = x * fmaf(GC1, x2, GC0);
    const float e  = __builtin_amdgcn_exp2f(z);
    const float sg = __builtin_amdgcn_rcpf(1.0f + e);
    return x * sg;
}

// ---------------------------------------------------------------------------
// histogram of dst; atomic return value IS the edge's rank in its bucket
// ---------------------------------------------------------------------------
__global__ void __launch_bounds__(256) hist_kernel(
    const int* __restrict__ dst, int* __restrict__ cursor,
    int* __restrict__ rank, int E)
{
    const int e4 = (blockIdx.x * 256 + threadIdx.x) * 4;
    if (e4 + 3 < E) {
        const int4 d = *(const int4*)(dst + e4);
        int4 r;
        r.x = atomicAdd(&cursor[d.x], 1);
        r.y = atomicAdd(&cursor[d.y], 1);
        r.z = atomicAdd(&cursor[d.z], 1);
        r.w = atomicAdd(&cursor[d.w], 1);
        *(int4*)(rank + e4) = r;
    } else {
        for (int e = e4; e < E; ++e) rank[e] = atomicAdd(&cursor[dst[e]], 1);
    }
}

// ---------------------------------------------------------------------------
// PARALLEL exclusive scan (decoupled lookback): grid of blocks, each block
// scans a 4096-elem chunk; stat[b] = (sum<<2)|state, state 1=aggregate,
// 2=inclusive-prefix. 25 blocks all co-resident -> no deadlock. Block 0
// wave 0 also computes the analytic-LN constants:
// fp[0..13] = ux,uy,uz,c, Gxx,Gxy,Gxz,Gyy,Gyz,Gzz, px,py,pz,q
// ---------------------------------------------------------------------------
__global__ void __launch_bounds__(1024) scan_kernel(
    const int* __restrict__ cursor, int* __restrict__ offsets,
    int* __restrict__ stat,
    const float* __restrict__ W1, const float* __restrict__ b1,
    float* __restrict__ fp, int N)
{
    const int t = threadIdx.x;
    const int b = blockIdx.x;
    if (b == 0 && t < 64) {
        const float w0 = W1[t], w1 = W1[HALF + t], w2 = W1[2 * HALF + t], bb = b1[t];
        float v[14] = { w0, w1, w2, bb,
                        w0 * w0, w0 * w1, w0 * w2, w1 * w1, w1 * w2, w2 * w2,
                        w0 * bb, w1 * bb, w2 * bb, bb * bb };
#pragma unroll
        for (int j = 0; j < 14; ++j) {
            float s = v[j];
#pragma unroll
            for (int off = 32; off; off >>= 1) s += __shfl_down(s, off, 64);
            if (t == 0) fp[j] = s * (1.0f / 64.0f);
        }
    }

    __shared__ int wtot[16];
    __shared__ int wexc[16];
    __shared__ int stot;
    __shared__ int sPref;
    const int w = t >> 6, lane = t & 63;

    const int i0 = b * 4096 + t * 4;
    int c[4];
    if (i0 + 3 < N) {
        *(int4*)c = *(const int4*)(cursor + i0);
    } else {
#pragma unroll
        for (int j = 0; j < 4; ++j) c[j] = (i0 + j < N) ? cursor[i0 + j] : 0;
    }
    const int s = c[0] + c[1] + c[2] + c[3];
    int incl = s;
#pragma unroll
    for (int off = 1; off < 64; off <<= 1) {
        const int v = __shfl_up(incl, off, 64);
        if (lane >= off) incl += v;
    }
    if (lane == 63) wtot[w] = incl;
    __syncthreads();
    if (t < 16) {
        const int v = wtot[t];
        int inc2 = v;
#pragma unroll
        for (int off = 1; off < 16; off <<= 1) {
            const int u = __shfl_up(inc2, off, 64);
            if (t >= off) inc2 += u;
        }
        wexc[t] = inc2 - v;
        if (t == 15) stot = inc2;
    }
    __syncthreads();

    if (t == 0) {
        const int S = stot;
        if (b == 0) {
            sPref = 0;
            __hip_atomic_store(&stat[0], (S << 2) | 2, __ATOMIC_RELEASE,
                               __HIP_MEMORY_SCOPE_AGENT);
        } else {
            __hip_atomic_store(&stat[b], (S << 2) | 1, __ATOMIC_RELEASE,
                               __HIP_MEMORY_SCOPE_AGENT);
            int running = 0;
            int j = b - 1;
            while (true) {
                const int v = __hip_atomic_load(&stat[j], __ATOMIC_ACQUIRE,
                                                __HIP_MEMORY_SCOPE_AGENT);
                const int st = v & 3;
                if (st == 0) continue;          // predecessor not published yet
                running += v >> 2;
                if (st == 2) break;             // hit a full prefix
                --j;
            }
            sPref = running;
            __hip_atomic_store(&stat[b], ((running + S) << 2) | 2,
                               __ATOMIC_RELEASE, __HIP_MEMORY_SCOPE_AGENT);
        }
    }
    __syncthreads();

    int run = sPref + wexc[w] + (incl - s);
#pragma unroll
    for (int j = 0; j < 4; ++j) {
        const int i = i0 + j;
        if (i < N) offsets[i] = run;
        run += c[j];
    }
    if (t == 0 && b == (int)gridDim.x - 1) offsets[N] = sPref + stot;
}

// ---------------------------------------------------------------------------
// fill (atomic-free): slot = offsets[dst] + rank[e]; geometry once per edge;
// scatter A[slot] grouped by dst (scatter absorbed by L2/L3 — A is 25.6 MB).
// ---------------------------------------------------------------------------
__global__ void __launch_bounds__(256) fill_kernel(
    const int* __restrict__ ei, const int* __restrict__ rank,
    const float* __restrict__ pos, const float* __restrict__ fp,
    const int* __restrict__ offsets, float4* __restrict__ A, int E)
{
    const int e4 = (blockIdx.x * 256 + threadIdx.x) * 4;
    if (e4 >= E) return;

    int se[4], de[4], re[4];
    if (e4 + 3 < E) {
        *(int4*)se = *(const int4*)(ei + e4);
        *(int4*)de = *(const int4*)(ei + E + e4);
        *(int4*)re = *(const int4*)(rank + e4);
    } else {
        for (int j = 0; j < 4; ++j) {
            const int e = e4 + j;
            se[j] = (e < E) ? ei[e] : 0;
            de[j] = (e < E) ? ei[E + e] : 0;
            re[j] = (e < E) ? rank[e] : 0;
        }
    }
    const float ux = fp[0], uy = fp[1], uz = fp[2], cc = fp[3];
    const float Gxx = fp[4], Gxy = fp[5], Gxz = fp[6];
    const float Gyy = fp[7], Gyz = fp[8], Gzz = fp[9];
    const float px = fp[10], py = fp[11], pz = fp[12], qq = fp[13];

#pragma unroll
    for (int j = 0; j < 4; ++j) {
        const int e = e4 + j;
        if (e >= E) break;
        const int s = se[j], d = de[j];
        const float rx0 = pos[3 * d + 0] - pos[3 * s + 0];
        const float ry0 = pos[3 * d + 1] - pos[3 * s + 1];
        const float rz0 = pos[3 * d + 2] - pos[3 * s + 2];
        const float dist = sqrtf(rx0 * rx0 + ry0 * ry0 + rz0 * rz0);
        const float inv  = 1.0f / (dist + 1e-6f);
        const float rx = rx0 * inv, ry = ry0 * inv, rz = rz0 * inv;

        const float mu  = fmaf(ux, rx, fmaf(uy, ry, fmaf(uz, rz, cc)));
        const float ev2 = Gxx * rx * rx + Gyy * ry * ry + Gzz * rz * rz
                        + 2.0f * (Gxy * rx * ry + Gxz * rx * rz + Gyz * ry * rz
                                  + px * rx + py * ry + pz * rz) + qq;
        const float rstd = rsqrtf(ev2 - mu * mu + LN_EPS);

        const int slot = offsets[d] + re[j];
        A[slot] = make_float4(rx * rstd, ry * rstd, rz * rstd, rstd);
    }
}

// ---------------------------------------------------------------------------
// FUSED node+out kernel v2: 16 nodes/block (4 waves x 4 nodes each).
// Phase 1 (per wave, lane=channel): software-pipelined edge loop — double-
// buffered 8x float4 chunks (cur/nxt, 64 VGPRs of data), always-prefetch one
// chunk ahead (A padded +16 makes this safe); tail chunk arrives pre-loaded.
// __launch_bounds__(256,4) raises VGPR cap to 128 so the compiler does NOT
// re-serialize the batch loads (previous build: VGPR=40 -> exposed L2 latency
// per pair of edges).
// Phase 2: sW2 LDS staging REMOVED — W2 read directly from global (L2-hot,
// 100 MB L2 traffic total ~3us); sh read as float4 (row pad 68: phase-1 write
// stays 2-way bank-free, b128 read 16B-aligned conflict-free). LDS instrs per
// wave drop ~144 -> ~16; LDS block 21KB -> 4.5KB.
// ---------------------------------------------------------------------------
__global__ void __launch_bounds__(256, 4) nodeout_kernel(
    const float4* __restrict__ A,        // [E+16] CSR-ordered (padded)
    const int* __restrict__ offsets,     // [N+1]
    const float* __restrict__ W1, const float* __restrict__ b1,
    const float* __restrict__ ln_g, const float* __restrict__ ln_b,
    const float* __restrict__ W2, const float* __restrict__ b2,
    const float* __restrict__ fp,
    float* __restrict__ out, int N)
{
    __shared__ float sh[16 * 68];        // 4352 B, pad 68: write 2-way-free,
    __shared__ int   sdeg[16];           // float4 read aligned + conflict-free
    const int tid = threadIdx.x;
    const int lane = tid & 63, w = tid >> 6;
    const float gl = ln_g[lane];
    const float C0 = gl * (W1[lane]            - fp[0]);
    const float C1 = gl * (W1[HALF + lane]     - fp[1]);
    const float C2 = gl * (W1[2 * HALF + lane] - fp[2]);
    const float C3 = gl * (b1[lane]            - fp[3]);
    const float Bl = ln_b[lane];

    const int base = blockIdx.x * 16;

    // hoist all 4 nodes' CSR bounds: 8 loads in flight together
    int begs[4], cnts[4];
#pragma unroll
    for (int q = 0; q < 4; ++q) {
        const int n = base + w * 4 + q;
        if (n < N) {
            begs[q] = offsets[n];
            cnts[q] = offsets[n + 1] - begs[q];
        } else { begs[q] = 0; cnts[q] = 0; }
    }

#pragma unroll
    for (int q = 0; q < 4; ++q) {
        const int r = w * 4 + q;
        const int cnt = cnts[q];
        const float4* p = A + begs[q];
        float accA = 0.0f, accB = 0.0f;

        float4 cur[8], nxt[8];
#pragma unroll
        for (int j = 0; j < 8; ++j) cur[j] = p[j];       // chunk 0 (pad-safe)
        const int full = cnt >> 3;
        const int rem  = cnt & 7;

        for (int c = 0; c < full; ++c) {                 // uniform scalar loop
            p += 8;
#pragma unroll
            for (int j = 0; j < 8; ++j) nxt[j] = p[j];   // prefetch next chunk
#pragma unroll
            for (int j = 0; j < 8; ++j) {
                const float x = fmaf(C0, cur[j].x, fmaf(C1, cur[j].y,
                                  fmaf(C2, cur[j].z, fmaf(C3, cur[j].w, Bl))));
                if (j & 1) accB += gelu_fast(x); else accA += gelu_fast(x);
            }
#pragma unroll
            for (int j = 0; j < 8; ++j) cur[j] = nxt[j];
        }
        if (rem) {                                       // tail: already loaded
#pragma unroll
            for (int j = 0; j < 8; ++j) {
                const float x = fmaf(C0, cur[j].x, fmaf(C1, cur[j].y,
                                  fmaf(C2, cur[j].z, fmaf(C3, cur[j].w, Bl))));
                const float g = gelu_fast(x);
                const float gm = (j < rem) ? g : 0.0f;   // NaN-safe select
                if (j & 1) accB += gm; else accA += gm;
            }
        }
        const float acc = accA + accB;
        sh[r * 68 + lane] = (cnt > 0) ? acc / (float)cnt : 0.0f;
        if (lane == 0) sdeg[r] = cnt;
    }
    __syncthreads();

    // Phase 2: 16x64 @ 64x64, thread = (node, 4 cols); W2 straight from L2.
    const int nl = tid >> 4;             // 0..15 local node
    const int cg = (tid & 15) * 4;       // 4 output cols
    const float4 bv = *(const float4*)(b2 + cg);
    const float* shrow = sh + nl * 68;
    const float* W2c = W2 + cg;
    float o0 = 0.0f, o1 = 0.0f, o2 = 0.0f, o3 = 0.0f;
#pragma unroll
    for (int k4 = 0; k4 < 16; ++k4) {
        const float4 hv = *(const float4*)(shrow + k4 * 4);
        const float4 wa = *(const float4*)(W2c + (k4 * 4 + 0) * HALF);
        const float4 wb = *(const float4*)(W2c + (k4 * 4 + 1) * HALF);
        const float4 wc = *(const float4*)(W2c + (k4 * 4 + 2) * HALF);
        const float4 wd = *(const float4*)(W2c + (k4 * 4 + 3) * HALF);
        o0 = fmaf(hv.x, wa.x, o0); o1 = fmaf(hv.x, wa.y, o1);
        o2 = fmaf(hv.x, wa.z, o2); o3 = fmaf(hv.x, wa.w, o3);
        o0 = fmaf(hv.y, wb.x, o0); o1 = fmaf(hv.y, wb.y, o1);
        o2 = fmaf(hv.y, wb.z, o2); o3 = fmaf(hv.y, wb.w, o3);
        o0 = fmaf(hv.z, wc.x, o0); o1 = fmaf(hv.z, wc.y, o1);
        o2 = fmaf(hv.z, wc.z, o2); o3 = fmaf(hv.z, wc.w, o3);
        o0 = fmaf(hv.w, wd.x, o0); o1 = fmaf(hv.w, wd.y, o1);
        o2 = fmaf(hv.w, wd.z, o2); o3 = fmaf(hv.w, wd.w, o3);
    }
    const int n = base + nl;
    if (n < N) {
        float4 res;
        if (sdeg[nl] > 0)
            res = make_float4(o0 + bv.x, o1 + bv.y, o2 + bv.z, o3 + bv.w);
        else
            res = make_float4(0.0f, 0.0f, 0.0f, 0.0f);
        float* orow = out + (size_t)n * (2 * HALF);
        *(float4*)(orow + cg) = res;
        *(float4*)(orow + HALF + cg) = make_float4(0.0f, 0.0f, 0.0f, 0.0f);
    }
}

// ---------------------------------------------------------------------------
extern "C" void kernel_launch(void* const* d_in, const int* in_sizes, int n_in,
                              void* d_out, int out_size, void* d_ws, size_t ws_size,
                              hipStream_t stream) {
    const float* pos = (const float*)d_in[0];
    const int*   ei  = (const int*)d_in[1];
    // d_in[2] = batch (unused)
    const float* W1  = (const float*)d_in[3];
    const float* b1  = (const float*)d_in[4];
    const float* g   = (const float*)d_in[5];
    const float* b   = (const float*)d_in[6];
    const float* W2  = (const float*)d_in[7];
    const float* b2  = (const float*)d_in[8];
    float* out = (float*)d_out;

    const int N = in_sizes[0] / 3;
    const int E = in_sizes[1] / 2;

    // workspace: A[E+16] f4 | cursor[N] | stat[32] | offsets[N+1] | fp[16] | rank[E]
    float4* A      = (float4*)d_ws;
    int* cursor    = (int*)(A + E + 16);
    int* stat      = cursor + N;
    int* offsets   = stat + 32;
    float* fparams = (float*)(offsets + N + 1);
    int* rank      = (int*)(fparams + 16);

    const int nb = (N + 4095) / 4096;    // 25 for N=100k (all co-resident)

    hipMemsetAsync(cursor, 0, (size_t)(N + 32) * sizeof(int), stream);
    hist_kernel<<<(E / 4 + 255) / 256, 256, 0, stream>>>(ei + E, cursor, rank, E);
    scan_kernel<<<nb, 1024, 0, stream>>>(cursor, offsets, stat, W1, b1, fparams, N);
    fill_kernel<<<(E / 4 + 255) / 256, 256, 0, stream>>>(ei, rank, pos, fparams,
                                                         offsets, A, E);
    nodeout_kernel<<<(N + 15) / 16, 256, 0, stream>>>(A, offsets, W1, b1, g, b,
                                                      W2, b2, fparams, out, N);
}

// Round 2
// 270.978 us; speedup vs baseline: 1.1495x; 1.1495x over previous
//
#include <hip/hip_runtime.h>
#include <math.h>

#define HALF 64
#define LN_EPS 1e-5f
#define SA_CAP 640   // staged float4 slots per block (10 KB); Poisson(256)+24sigma

// gelu_tanh(x) = x * sigmoid(1.5957691*x + 0.0713549*x^3)
#define GC0 -2.3022082f
#define GC1 -0.1029438f

__device__ __forceinline__ float gelu_fast(float x) {
    const float x2 = x * x;
    const float z  = x * fmaf(GC1, x2, GC0);
    const float e  = __builtin_amdgcn_exp2f(z);
    const float sg = __builtin_amdgcn_rcpf(1.0f + e);
    return x * sg;
}

// ---------------------------------------------------------------------------
// histogram of dst; atomic return value IS the edge's rank in its bucket
// ---------------------------------------------------------------------------
__global__ void __launch_bounds__(256) hist_kernel(
    const int* __restrict__ dst, int* __restrict__ cursor,
    int* __restrict__ rank, int E)
{
    const int e4 = (blockIdx.x * 256 + threadIdx.x) * 4;
    if (e4 + 3 < E) {
        const int4 d = *(const int4*)(dst + e4);
        int4 r;
        r.x = atomicAdd(&cursor[d.x], 1);
        r.y = atomicAdd(&cursor[d.y], 1);
        r.z = atomicAdd(&cursor[d.z], 1);
        r.w = atomicAdd(&cursor[d.w], 1);
        *(int4*)(rank + e4) = r;
    } else {
        for (int e = e4; e < E; ++e) rank[e] = atomicAdd(&cursor[dst[e]], 1);
    }
}

// ---------------------------------------------------------------------------
// PARALLEL exclusive scan (decoupled lookback): grid of blocks, each block
// scans a 4096-elem chunk; stat[b] = (sum<<2)|state, state 1=aggregate,
// 2=inclusive-prefix. 25 blocks all co-resident -> no deadlock. Block 0
// wave 0 also computes the analytic-LN constants:
// fp[0..13] = ux,uy,uz,c, Gxx,Gxy,Gxz,Gyy,Gyz,Gzz, px,py,pz,q
// ---------------------------------------------------------------------------
__global__ void __launch_bounds__(1024) scan_kernel(
    const int* __restrict__ cursor, int* __restrict__ offsets,
    int* __restrict__ stat,
    const float* __restrict__ W1, const float* __restrict__ b1,
    float* __restrict__ fp, int N)
{
    const int t = threadIdx.x;
    const int b = blockIdx.x;
    if (b == 0 && t < 64) {
        const float w0 = W1[t], w1 = W1[HALF + t], w2 = W1[2 * HALF + t], bb = b1[t];
        float v[14] = { w0, w1, w2, bb,
                        w0 * w0, w0 * w1, w0 * w2, w1 * w1, w1 * w2, w2 * w2,
                        w0 * bb, w1 * bb, w2 * bb, bb * bb };
#pragma unroll
        for (int j = 0; j < 14; ++j) {
            float s = v[j];
#pragma unroll
            for (int off = 32; off; off >>= 1) s += __shfl_down(s, off, 64);
            if (t == 0) fp[j] = s * (1.0f / 64.0f);
        }
    }

    __shared__ int wtot[16];
    __shared__ int wexc[16];
    __shared__ int stot;
    __shared__ int sPref;
    const int w = t >> 6, lane = t & 63;

    const int i0 = b * 4096 + t * 4;
    int c[4];
    if (i0 + 3 < N) {
        *(int4*)c = *(const int4*)(cursor + i0);
    } else {
#pragma unroll
        for (int j = 0; j < 4; ++j) c[j] = (i0 + j < N) ? cursor[i0 + j] : 0;
    }
    const int s = c[0] + c[1] + c[2] + c[3];
    int incl = s;
#pragma unroll
    for (int off = 1; off < 64; off <<= 1) {
        const int v = __shfl_up(incl, off, 64);
        if (lane >= off) incl += v;
    }
    if (lane == 63) wtot[w] = incl;
    __syncthreads();
    if (t < 16) {
        const int v = wtot[t];
        int inc2 = v;
#pragma unroll
        for (int off = 1; off < 16; off <<= 1) {
            const int u = __shfl_up(inc2, off, 64);
            if (t >= off) inc2 += u;
        }
        wexc[t] = inc2 - v;
        if (t == 15) stot = inc2;
    }
    __syncthreads();

    if (t == 0) {
        const int S = stot;
        if (b == 0) {
            sPref = 0;
            __hip_atomic_store(&stat[0], (S << 2) | 2, __ATOMIC_RELEASE,
                               __HIP_MEMORY_SCOPE_AGENT);
        } else {
            __hip_atomic_store(&stat[b], (S << 2) | 1, __ATOMIC_RELEASE,
                               __HIP_MEMORY_SCOPE_AGENT);
            int running = 0;
            int j = b - 1;
            while (true) {
                const int v = __hip_atomic_load(&stat[j], __ATOMIC_ACQUIRE,
                                                __HIP_MEMORY_SCOPE_AGENT);
                const int st = v & 3;
                if (st == 0) continue;          // predecessor not published yet
                running += v >> 2;
                if (st == 2) break;             // hit a full prefix
                --j;
            }
            sPref = running;
            __hip_atomic_store(&stat[b], ((running + S) << 2) | 2,
                               __ATOMIC_RELEASE, __HIP_MEMORY_SCOPE_AGENT);
        }
    }
    __syncthreads();

    int run = sPref + wexc[w] + (incl - s);
#pragma unroll
    for (int j = 0; j < 4; ++j) {
        const int i = i0 + j;
        if (i < N) offsets[i] = run;
        run += c[j];
    }
    if (t == 0 && b == (int)gridDim.x - 1) offsets[N] = sPref + stot;
}

// ---------------------------------------------------------------------------
// fill (atomic-free): slot = offsets[dst] + rank[e]; geometry once per edge;
// scatter A[slot] grouped by dst (scatter absorbed by L2/L3 — A is 25.6 MB).
// ---------------------------------------------------------------------------
__global__ void __launch_bounds__(256) fill_kernel(
    const int* __restrict__ ei, const int* __restrict__ rank,
    const float* __restrict__ pos, const float* __restrict__ fp,
    const int* __restrict__ offsets, float4* __restrict__ A, int E)
{
    const int e4 = (blockIdx.x * 256 + threadIdx.x) * 4;
    if (e4 >= E) return;

    int se[4], de[4], re[4];
    if (e4 + 3 < E) {
        *(int4*)se = *(const int4*)(ei + e4);
        *(int4*)de = *(const int4*)(ei + E + e4);
        *(int4*)re = *(const int4*)(rank + e4);
    } else {
        for (int j = 0; j < 4; ++j) {
            const int e = e4 + j;
            se[j] = (e < E) ? ei[e] : 0;
            de[j] = (e < E) ? ei[E + e] : 0;
            re[j] = (e < E) ? rank[e] : 0;
        }
    }
    const float ux = fp[0], uy = fp[1], uz = fp[2], cc = fp[3];
    const float Gxx = fp[4], Gxy = fp[5], Gxz = fp[6];
    const float Gyy = fp[7], Gyz = fp[8], Gzz = fp[9];
    const float px = fp[10], py = fp[11], pz = fp[12], qq = fp[13];

#pragma unroll
    for (int j = 0; j < 4; ++j) {
        const int e = e4 + j;
        if (e >= E) break;
        const int s = se[j], d = de[j];
        const float rx0 = pos[3 * d + 0] - pos[3 * s + 0];
        const float ry0 = pos[3 * d + 1] - pos[3 * s + 1];
        const float rz0 = pos[3 * d + 2] - pos[3 * s + 2];
        const float dist = sqrtf(rx0 * rx0 + ry0 * ry0 + rz0 * rz0);
        const float inv  = 1.0f / (dist + 1e-6f);
        const float rx = rx0 * inv, ry = ry0 * inv, rz = rz0 * inv;

        const float mu  = fmaf(ux, rx, fmaf(uy, ry, fmaf(uz, rz, cc)));
        const float ev2 = Gxx * rx * rx + Gyy * ry * ry + Gzz * rz * rz
                        + 2.0f * (Gxy * rx * ry + Gxz * rx * rz + Gyz * ry * rz
                                  + px * rx + py * ry + pz * rz) + qq;
        const float rstd = rsqrtf(ev2 - mu * mu + LN_EPS);

        const int slot = offsets[d] + re[j];
        A[slot] = make_float4(rx * rstd, ry * rstd, rz * rstd, rstd);
    }
}

// ---------------------------------------------------------------------------
// FUSED node+out kernel v3: 16 nodes/block (4 waves x 4 nodes each).
// Key fix vs v1/v2: the block's A-range is CONTIGUOUS (CSR order) — stage it
// into LDS with coalesced float4 loads (avg 4 KB/block, cap 10 KB, block-
// uniform global fallback for pathological degree sums). The per-edge
// wave-uniform read becomes a conflict-free broadcast ds_read_b128 (~12 cy)
// instead of an exposed L2/L3 round-trip that the compiler refused to
// pipeline at its chosen VGPR budget (r0: VGPR=40; r1 dbuf attempt: VGPR=48,
// still serialized, -34%). W2 LDS staging RESTORED (removing it was the r1
// regression: 64 serialized global loads/thread in phase 2).
// LDS ~31.4 KB -> 5 blocks/CU.
// ---------------------------------------------------------------------------
__global__ void __launch_bounds__(256, 4) nodeout_kernel(
    const float4* __restrict__ A,        // [E+16] CSR-ordered (padded)
    const int* __restrict__ offsets,     // [N+1]
    const float* __restrict__ W1, const float* __restrict__ b1,
    const float* __restrict__ ln_g, const float* __restrict__ ln_b,
    const float* __restrict__ W2, const float* __restrict__ b2,
    const float* __restrict__ fp,
    float* __restrict__ out, int N)
{
    __shared__ float  sW2[HALF * HALF];  // 16 KB
    __shared__ float  sb2[HALF];
    __shared__ float  sh[16 * 68];       // pitch 68: f4-aligned, conflict-free
    __shared__ int    sdeg[16];
    __shared__ float4 sA[SA_CAP + 8];    // 10.1 KB (+8 pad for chunk overread)

    const int tid = threadIdx.x;
    for (int i = tid; i < HALF * HALF; i += 256) sW2[i] = W2[i];
    if (tid < HALF) sb2[tid] = b2[tid];

    const int lane = tid & 63, w = tid >> 6;
    const float gl = ln_g[lane];
    const float C0 = gl * (W1[lane]            - fp[0]);
    const float C1 = gl * (W1[HALF + lane]     - fp[1]);
    const float C2 = gl * (W1[2 * HALF + lane] - fp[2]);
    const float C3 = gl * (b1[lane]            - fp[3]);
    const float Bl = ln_b[lane];

    const int base = blockIdx.x * 16;
    const int nend = (base + 16 < N) ? base + 16 : N;
    const int begB = offsets[base];
    const int cntB = offsets[nend] - begB;

    // hoist all 4 nodes' CSR bounds
    int begs[4], cnts[4];
#pragma unroll
    for (int q = 0; q < 4; ++q) {
        const int n = base + w * 4 + q;
        if (n < N) {
            begs[q] = offsets[n];
            cnts[q] = offsets[n + 1] - begs[q];
        } else { begs[q] = 0; cnts[q] = 0; }
    }

    if (cntB <= SA_CAP) {
        // ---- fast path: coalesced stage of the whole block range ----
        for (int i = tid; i < cntB; i += 256) sA[i] = A[begB + i];
        __syncthreads();

#pragma unroll
        for (int q = 0; q < 4; ++q) {
            const int r = w * 4 + q;
            const int cnt = cnts[q];
            const float4* p = sA + (begs[q] - begB);   // LDS, broadcast reads
            float accA = 0.0f, accB = 0.0f;
            int i = 0;
            for (; i + 8 <= cnt; i += 8) {
                float4 aa[8];
#pragma unroll
                for (int j = 0; j < 8; ++j) aa[j] = p[i + j];
#pragma unroll
                for (int j = 0; j < 8; ++j) {
                    const float x = fmaf(C0, aa[j].x, fmaf(C1, aa[j].y,
                                      fmaf(C2, aa[j].z, fmaf(C3, aa[j].w, Bl))));
                    if (j & 1) accB += gelu_fast(x); else accA += gelu_fast(x);
                }
            }
            if (i < cnt) {                            // tail (<8), pad-safe
                const int rem = cnt - i;
                float4 aa[8];
#pragma unroll
                for (int j = 0; j < 8; ++j) aa[j] = p[i + j];
#pragma unroll
                for (int j = 0; j < 8; ++j) {
                    const float x = fmaf(C0, aa[j].x, fmaf(C1, aa[j].y,
                                      fmaf(C2, aa[j].z, fmaf(C3, aa[j].w, Bl))));
                    const float g = gelu_fast(x);
                    const float gm = (j < rem) ? g : 0.0f;
                    if (j & 1) accB += gm; else accA += gm;
                }
            }
            const float acc = accA + accB;
            sh[r * 68 + lane] = (cnt > 0) ? acc / (float)cnt : 0.0f;
            if (lane == 0) sdeg[r] = cnt;
        }
    } else {
        // ---- fallback (block-uniform, ~never): direct global reads ----
        __syncthreads();
#pragma unroll
        for (int q = 0; q < 4; ++q) {
            const int r = w * 4 + q;
            const int cnt = cnts[q];
            const float4* p = A + begs[q];            // +16 pad makes overread safe
            float accA = 0.0f, accB = 0.0f;
            int i = 0;
            for (; i + 8 <= cnt; i += 8) {
                float4 aa[8];
#pragma unroll
                for (int j = 0; j < 8; ++j) aa[j] = p[i + j];
#pragma unroll
                for (int j = 0; j < 8; ++j) {
                    const float x = fmaf(C0, aa[j].x, fmaf(C1, aa[j].y,
                                      fmaf(C2, aa[j].z, fmaf(C3, aa[j].w, Bl))));
                    if (j & 1) accB += gelu_fast(x); else accA += gelu_fast(x);
                }
            }
            if (i < cnt) {
                const int rem = cnt - i;
                float4 aa[8];
#pragma unroll
                for (int j = 0; j < 8; ++j) aa[j] = p[i + j];
#pragma unroll
                for (int j = 0; j < 8; ++j) {
                    const float x = fmaf(C0, aa[j].x, fmaf(C1, aa[j].y,
                                      fmaf(C2, aa[j].z, fmaf(C3, aa[j].w, Bl))));
                    const float g = gelu_fast(x);
                    const float gm = (j < rem) ? g : 0.0f;
                    if (j & 1) accB += gm; else accA += gm;
                }
            }
            const float acc = accA + accB;
            sh[r * 68 + lane] = (cnt > 0) ? acc / (float)cnt : 0.0f;
            if (lane == 0) sdeg[r] = cnt;
        }
    }
    __syncthreads();

    // Phase 2: 16x64 @ 64x64, thread = (node, 4 cols), all operands in LDS.
    const int nl = tid >> 4;             // 0..15 local node
    const int cg = (tid & 15) * 4;       // 4 output cols
    const float* shrow = sh + nl * 68;
    float o0 = 0.0f, o1 = 0.0f, o2 = 0.0f, o3 = 0.0f;
#pragma unroll
    for (int k4 = 0; k4 < 16; ++k4) {
        const float4 hv = *(const float4*)(shrow + k4 * 4);
        const float4 wa = *(const float4*)(sW2 + (k4 * 4 + 0) * HALF + cg);
        const float4 wb = *(const float4*)(sW2 + (k4 * 4 + 1) * HALF + cg);
        const float4 wc = *(const float4*)(sW2 + (k4 * 4 + 2) * HALF + cg);
        const float4 wd = *(const float4*)(sW2 + (k4 * 4 + 3) * HALF + cg);
        o0 = fmaf(hv.x, wa.x, o0); o1 = fmaf(hv.x, wa.y, o1);
        o2 = fmaf(hv.x, wa.z, o2); o3 = fmaf(hv.x, wa.w, o3);
        o0 = fmaf(hv.y, wb.x, o0); o1 = fmaf(hv.y, wb.y, o1);
        o2 = fmaf(hv.y, wb.z, o2); o3 = fmaf(hv.y, wb.w, o3);
        o0 = fmaf(hv.z, wc.x, o0); o1 = fmaf(hv.z, wc.y, o1);
        o2 = fmaf(hv.z, wc.z, o2); o3 = fmaf(hv.z, wc.w, o3);
        o0 = fmaf(hv.w, wd.x, o0); o1 = fmaf(hv.w, wd.y, o1);
        o2 = fmaf(hv.w, wd.z, o2); o3 = fmaf(hv.w, wd.w, o3);
    }
    const int n = base + nl;
    if (n < N) {
        float4 res;
        if (sdeg[nl] > 0)
            res = make_float4(o0 + sb2[cg], o1 + sb2[cg + 1],
                              o2 + sb2[cg + 2], o3 + sb2[cg + 3]);
        else
            res = make_float4(0.0f, 0.0f, 0.0f, 0.0f);
        float* orow = out + (size_t)n * (2 * HALF);
        *(float4*)(orow + cg) = res;
        *(float4*)(orow + HALF + cg) = make_float4(0.0f, 0.0f, 0.0f, 0.0f);
    }
}

// ---------------------------------------------------------------------------
extern "C" void kernel_launch(void* const* d_in, const int* in_sizes, int n_in,
                              void* d_out, int out_size, void* d_ws, size_t ws_size,
                              hipStream_t stream) {
    const float* pos = (const float*)d_in[0];
    const int*   ei  = (const int*)d_in[1];
    // d_in[2] = batch (unused)
    const float* W1  = (const float*)d_in[3];
    const float* b1  = (const float*)d_in[4];
    const float* g   = (const float*)d_in[5];
    const float* b   = (const float*)d_in[6];
    const float* W2  = (const float*)d_in[7];
    const float* b2  = (const float*)d_in[8];
    float* out = (float*)d_out;

    const int N = in_sizes[0] / 3;
    const int E = in_sizes[1] / 2;

    // workspace: A[E+16] f4 | cursor[N] | stat[32] | offsets[N+1] | fp[16] | rank[E]
    float4* A      = (float4*)d_ws;
    int* cursor    = (int*)(A + E + 16);
    int* stat      = cursor + N;
    int* offsets   = stat + 32;
    float* fparams = (float*)(offsets + N + 1);
    int* rank      = (int*)(fparams + 16);

    const int nb = (N + 4095) / 4096;    // 25 for N=100k (all co-resident)

    hipMemsetAsync(cursor, 0, (size_t)(N + 32) * sizeof(int), stream);
    hist_kernel<<<(E / 4 + 255) / 256, 256, 0, stream>>>(ei + E, cursor, rank, E);
    scan_kernel<<<nb, 1024, 0, stream>>>(cursor, offsets, stat, W1, b1, fparams, N);
    fill_kernel<<<(E / 4 + 255) / 256, 256, 0, stream>>>(ei, rank, pos, fparams,
                                                         offsets, A, E);
    nodeout_kernel<<<(N + 15) / 16, 256, 0, stream>>>(A, offsets, W1, b1, g, b,
                                                      W2, b2, fparams, out, N);
}